// Round 6
// baseline (183.802 us; speedup 1.0000x reference)
//
#include <hip/hip_runtime.h>

// DGCN layer: out = ((A_norm @ (h * outdeg^-.5)) * indeg^-1.5) @ W + bias
// R15: k_pagg gather rebuilt on global_load_lds. Rows stream directly
// HBM/L2 -> LDS with zero VGPR cost per outstanding load (R11/R13 proved the
// RA won't hold deep gather batches). Each wave runs a private double-
// buffered pipeline: issue batch t+1 (4x gload_lds, 16 edges) -> counted
// s_waitcnt vmcnt(4) -> compute batch t from LDS (ds_read_b128 + fma_mix).
// No barriers in the loop (per-wave buffers). LDS 15.4->51 KB, 3 blocks/CU.
// k_combo = R14 exactly. scoef precompute kept (R14 win).
// Pipeline: memset(gcur+gdeg) + combo(partition|hist|Wcast|hcast) + pagg.

constexpr int D = 128;
constexpr int HC = 32;        // histogram copies
constexpr int PNODES = 32;    // dst-nodes per partition
constexpr int PCAP = 768;     // edge capacity per partition (mean 512, +11 sigma)
constexpr int CHUNK = 8192;   // edges per partition-sort block
constexpr int NCAST = 384;    // h-cast backfill blocks

typedef __attribute__((ext_vector_type(8))) short bf16x8;
typedef __attribute__((ext_vector_type(4))) float f32x4;
typedef __attribute__((ext_vector_type(2))) _Float16 f16x2;

__device__ __forceinline__ float bf16_to_f(unsigned int u16) {
    union { unsigned int u; float f; } c; c.u = u16 << 16; return c.f;
}
__device__ __forceinline__ unsigned int f_to_bf16(float f) {
    union { float f; unsigned int u; } c; c.f = f;
    unsigned int u = c.u;
    u += 0x7fffu + ((u >> 16) & 1u);   // RNE
    return u >> 16;
}
__device__ __forceinline__ unsigned int pack_f16x2(float x, float y) {
    f16x2 p; p.x = (_Float16)x; p.y = (_Float16)y;   // RNE cvt
    union { f16x2 h; unsigned int u; } c; c.h = p; return c.u;
}
__device__ __forceinline__ void gload16(const void* g, void* l) {
    __builtin_amdgcn_global_load_lds(
        (const __attribute__((address_space(1))) void*)g,
        (__attribute__((address_space(3))) void*)l, 16, 0, 0);
}

// ---- combined kernel, role by blockIdx:
//   [0, nbA)           partition edges by dst (chunked LDS counting sort)
//   [nbA, nbA+HC)      out-degree histogram (packed u16 bins) + atomic reduce
//   nbA+HC             W fp32 -> Wt bf16 transposed
//   (nbA+HC, ...]      h fp32 -> hs fp16 (unscaled) ----
__global__ __launch_bounds__(256) void k_combo(const int* __restrict__ src,
        const int* __restrict__ dst, const int* __restrict__ dist,
        int* __restrict__ gcur, unsigned int* __restrict__ gbuf,
        unsigned int* __restrict__ gdeg,
        const float4* __restrict__ h4, uint4* __restrict__ hs4,
        const float* __restrict__ W, unsigned short* __restrict__ Wt,
        int E, int N, int NW, int hchunk, int P, int nbA) {
    extern __shared__ int dyn[];
    int tid = threadIdx.x;
    int bi = blockIdx.x;

    if (bi >= nbA + HC) {
        if (bi == nbA + HC) {    // W[k][n] fp32 -> Wt[n*128+k] bf16
            for (int i = tid; i < D * D; i += 256) {
                int k = i >> 7, n = i & 127;
                Wt[n * D + k] = (unsigned short)f_to_bf16(W[i]);
            }
            return;
        }
        // ---- hcast role: hs = fp16(h), grid-stride over 8-float groups ----
        int cb = bi - (nbA + HC + 1);
        int G = N * (D / 8);
        for (int i = cb * 256 + tid; i < G; i += NCAST * 256) {
            float4 a = h4[2 * i];
            float4 b = h4[2 * i + 1];
            uint4 o;
            o.x = pack_f16x2(a.x, a.y);
            o.y = pack_f16x2(a.z, a.w);
            o.z = pack_f16x2(b.x, b.y);
            o.w = pack_f16x2(b.z, b.w);
            hs4[i] = o;
        }
        return;
    }

    if (bi >= nbA) {
        // ---- hist role: whole-N packed 16-bit histogram in LDS ----
        unsigned int* bins = (unsigned int*)dyn;
        for (int i = tid; i < NW; i += 256) bins[i] = 0;
        __syncthreads();
        int c = bi - nbA;
        int e0 = c * hchunk, e1 = min(e0 + hchunk, E);
        for (int i = e0 + tid * 4; i < e1; i += 1024) {
            if (i + 3 < e1) {
                int4 k4 = *(const int4*)&src[i];
                atomicAdd(&bins[k4.x >> 1], 1u << ((k4.x & 1) * 16));
                atomicAdd(&bins[k4.y >> 1], 1u << ((k4.y & 1) * 16));
                atomicAdd(&bins[k4.z >> 1], 1u << ((k4.z & 1) * 16));
                atomicAdd(&bins[k4.w >> 1], 1u << ((k4.w & 1) * 16));
            } else {
                for (int e = i; e < e1; e++)
                    atomicAdd(&bins[src[e] >> 1], 1u << ((src[e] & 1) * 16));
            }
        }
        __syncthreads();
        // reduce in place: packed u32 add is exact (halves never carry)
        for (int i = tid; i < NW; i += 256) {
            unsigned int v = bins[i];
            if (v) atomicAdd(&gdeg[i], v);
        }
        return;
    }

    // ---- partition role: chunked counting sort into 32-node dst buckets ----
    // Packed edge word: src (16b) | dst_lo (5b @16) | dist (3b @21).
    unsigned int* sorted = (unsigned int*)dyn;            // CHUNK
    int* gidx  = dyn + CHUNK;                             // CHUNK
    int* hist  = dyn + 2 * CHUNK;                         // P
    int* start = hist + P;
    int* lofs  = start + P;
    int* base_g = lofs + P;
    __shared__ int wsum[4];

    int lane = tid & 63, w = tid >> 6;
    int e0 = bi * CHUNK;
    int e1 = min(e0 + CHUNK, E);
    int ce = e1 - e0;

    for (int b = tid; b < P; b += 256) hist[b] = 0;
    __syncthreads();

    // phase 1: histogram dst partitions
    for (int i = e0 + tid * 4; i < e1; i += 1024) {
        if (i + 3 < e1) {
            int4 d4 = *(const int4*)&dst[i];
            atomicAdd(&hist[d4.x >> 5], 1);
            atomicAdd(&hist[d4.y >> 5], 1);
            atomicAdd(&hist[d4.z >> 5], 1);
            atomicAdd(&hist[d4.w >> 5], 1);
        } else {
            for (int e = i; e < e1; e++) atomicAdd(&hist[dst[e] >> 5], 1);
        }
    }
    __syncthreads();

    // phase 2: scan (7 bins/thread) + global reservation
    int loc[7];
    int s = 0;
    #pragma unroll
    for (int j = 0; j < 7; j++) {
        int b = tid * 7 + j;
        int v = (b < P) ? hist[b] : 0;
        loc[j] = s;
        s += v;
    }
    int x = s;
    #pragma unroll
    for (int off = 1; off < 64; off <<= 1) {
        int t = __shfl_up(x, off, 64);
        if (lane >= off) x += t;
    }
    if (lane == 63) wsum[w] = x;
    __syncthreads();
    int tbase = x - s;
    #pragma unroll
    for (int k = 0; k < 4; k++) if (k < w) tbase += wsum[k];
    #pragma unroll
    for (int j = 0; j < 7; j++) {
        int b = tid * 7 + j;
        if (b < P) {
            int st = tbase + loc[j];
            start[b] = st;
            lofs[b] = st;
            int cnt = hist[b];
            if (cnt) base_g[b] = atomicAdd(&gcur[b], cnt);
        }
    }
    __syncthreads();

    // phase 3: re-read edges (L2-hot), place into LDS order + targets
    for (int i = e0 + tid * 4; i < e1; i += 1024) {
        if (i + 3 < e1) {
            int4 s4 = *(const int4*)&src[i];
            int4 d4 = *(const int4*)&dst[i];
            int4 q4 = *(const int4*)&dist[i];
            #pragma unroll
            for (int j = 0; j < 4; j++) {
                int sv = (&s4.x)[j], dv = (&d4.x)[j], qv = (&q4.x)[j];
                int p = dv >> 5;
                unsigned int wd = (unsigned)sv | ((unsigned)(dv & 31) << 16)
                                | ((unsigned)qv << 21);
                int pos = atomicAdd(&lofs[p], 1);
                sorted[pos] = wd;
                int rank = base_g[p] + (pos - start[p]);
                gidx[pos] = (rank < PCAP) ? p * PCAP + rank : -1;
            }
        } else {
            for (int e = i; e < e1; e++) {
                int sv = src[e], dv = dst[e], qv = dist[e];
                int p = dv >> 5;
                unsigned int wd = (unsigned)sv | ((unsigned)(dv & 31) << 16)
                                | ((unsigned)qv << 21);
                int pos = atomicAdd(&lofs[p], 1);
                sorted[pos] = wd;
                int rank = base_g[p] + (pos - start[p]);
                gidx[pos] = (rank < PCAP) ? p * PCAP + rank : -1;
            }
        }
    }
    __syncthreads();

    // phase 4: run-coalesced copy-out
    for (int i = tid; i < ce; i += 256) {
        int g = gidx[i];
        if (g >= 0) gbuf[g] = sorted[i];
    }
}

// ---- per-partition aggregate + fused MFMA GEMM epilogue ----
// Edges LDS-sorted by node. Per wave: private double-buffered stage pipeline:
// issue 16-edge batch t+1 via 4x global_load_lds (1KB each, zero VGPR), then
// s_waitcnt vmcnt(4) (counted: batch t drained, t+1 in flight), then compute
// batch t from LDS (4x ds_read_b128 per lane + v_fma_mix, f32 acc). No
// barriers in the loop. scoef[] precomputed at slist build (R14).
// 32x128 agg -> As -> MFMA with L2-resident Wt. 3 blocks/CU (51KB LDS).
__global__ __launch_bounds__(256, 3) void k_pagg(const uint4* __restrict__ hs4,
        const unsigned int* __restrict__ gbuf, const int* __restrict__ gcur,
        const unsigned short* __restrict__ gdeg16,
        const unsigned short* __restrict__ Wt, const float* __restrict__ bias,
        float* __restrict__ out, int N) {
    __shared__ unsigned int elist[PCAP];
    __shared__ unsigned int slist[PCAP];
    __shared__ float scoef[PCAP];
    __shared__ int h2[PNODES], st2[PNODES], lo2[PNODES];
    __shared__ unsigned short As[PNODES * 136];
    __shared__ char stage[4 * 2 * 4096];     // [wave][buf][16 edges x 256B]
    int p = blockIdx.x;
    int tid = threadIdx.x;
    int cnt = min(gcur[p], PCAP);
    const unsigned int* gp = gbuf + (size_t)p * PCAP;

    if (tid < PNODES) h2[tid] = 0;
    __syncthreads();
    for (int i = tid; i < cnt; i += 256) {
        unsigned int wd = gp[i];
        elist[i] = wd;
        atomicAdd(&h2[(wd >> 16) & 31], 1);
    }
    __syncthreads();
    if (tid < 64) {   // wave 0 scans 32 bins
        int v = (tid < PNODES) ? h2[tid] : 0;
        int x = v;
        #pragma unroll
        for (int off = 1; off < 32; off <<= 1) {
            int t = __shfl_up(x, off, 64);
            if ((tid & 63) >= off) x += t;
        }
        if (tid < PNODES) { st2[tid] = x - v; lo2[tid] = x - v; }
    }
    __syncthreads();
    for (int i = tid; i < cnt; i += 256) {
        unsigned int wd = elist[i];
        int pos = atomicAdd(&lo2[(wd >> 16) & 31], 1);
        slist[pos] = wd;
        unsigned int sv = wd & 0xffffu;
        float os = rsqrtf((float)gdeg16[sv]);             // outdeg^-0.5 (once)
        scoef[pos] = __uint_as_float((127u - ((wd >> 21) & 7u)) << 23) * os;
    }
    __syncthreads();

    int wv = tid >> 6, l64 = tid & 63;
    int lane16 = l64 & 15, sub = l64 >> 4;   // edge slot group 0..3
    int wb = wv * 8;                         // this wave's first node
    char* swave = stage + wv * 8192;         // per-wave stage region

    // issue one 16-edge batch into LDS buffer (4 x global_load_lds, 1KB each)
    auto issue = [&](char* lbase, int b, int deg, int eo) {
        #pragma unroll
        for (int i = 0; i < 4; i++) {
            int s = eo + i * 4 + sub;
            int ei = b + min(s, deg - 1);
            unsigned int sv = slist[ei] & 0xffffu;
            gload16(&hs4[(sv << 4) + (unsigned)lane16], lbase + i * 1024);
        }
    };

    // wave-private pipelined gather over this wave's 8 nodes
    int k = 0;
    while (k < 8 && h2[wb + k] == 0) k++;
    int eo = 0, buf = 0;
    if (k < 8) issue(swave, st2[wb + k], h2[wb + k], 0);
    float acc[8] = {0.f, 0.f, 0.f, 0.f, 0.f, 0.f, 0.f, 0.f};
    while (k < 8) {
        int deg = h2[wb + k], b = st2[wb + k];
        // lookahead: next batch (possibly next node)
        int kn = k, eon = eo + 16;
        if (eon >= deg) {
            eon = 0; kn = k + 1;
            while (kn < 8 && h2[wb + kn] == 0) kn++;
        }
        bool hn = kn < 8;
        if (hn) issue(swave + (buf ^ 1) * 4096, st2[wb + kn], h2[wb + kn], eon);
        if (hn) asm volatile("s_waitcnt vmcnt(4)" ::: "memory");
        else    asm volatile("s_waitcnt vmcnt(0)" ::: "memory");
        // compute current batch from LDS
        const char* cbase = swave + buf * 4096;
        #pragma unroll
        for (int j = 0; j < 4; j++) {
            int s = eo + j * 4 + sub;
            bool valid = s < deg;
            uint4 hv = *(const uint4*)(cbase + (j * 4 + sub) * 256 + lane16 * 16);
            float c = scoef[b + min(s, deg - 1)];
            c = valid ? c : 0.f;
            const f16x2* hp = (const f16x2*)&hv;
            #pragma unroll
            for (int q = 0; q < 4; q++) {
                acc[2 * q]     = fmaf((float)hp[q].x, c, acc[2 * q]);
                acc[2 * q + 1] = fmaf((float)hp[q].y, c, acc[2 * q + 1]);
            }
        }
        if (eo + 16 >= deg) {   // node finished: fold 4 slots, store As row
            #pragma unroll
            for (int j = 0; j < 8; j++) {
                acc[j] += __shfl_xor(acc[j], 16, 64);
                acc[j] += __shfl_xor(acc[j], 32, 64);
            }
            if (sub == 0) {
                uint4 o = make_uint4(0u, 0u, 0u, 0u);
                if (p * PNODES + wb + k < N) {
                    float fd = (float)deg;
                    float sc = rsqrtf(fd) / fd;   // indeg^-1.5
                    o.x = f_to_bf16(acc[0] * sc) | (f_to_bf16(acc[1] * sc) << 16);
                    o.y = f_to_bf16(acc[2] * sc) | (f_to_bf16(acc[3] * sc) << 16);
                    o.z = f_to_bf16(acc[4] * sc) | (f_to_bf16(acc[5] * sc) << 16);
                    o.w = f_to_bf16(acc[6] * sc) | (f_to_bf16(acc[7] * sc) << 16);
                }
                *(uint4*)&As[(wb + k) * 136 + lane16 * 8] = o;
            }
            #pragma unroll
            for (int j = 0; j < 8; j++) acc[j] = 0.f;
        }
        k = kn; eo = eon; buf ^= 1;
    }
    // padding nodes (deg==0) of the last partition: zero their As rows
    #pragma unroll
    for (int kk = 0; kk < 8; kk++) {
        if (h2[wb + kk] == 0 && sub == 0)
            *(uint4*)&As[(wb + kk) * 136 + lane16 * 8] = make_uint4(0u, 0u, 0u, 0u);
    }
    __syncthreads();

    // MFMA: wave w -> row-tile mt = w&1, col-tiles nt = (w>>1)*4 + t
    int m = l64 & 15, quad = l64 >> 4;
    int mt = wv & 1, ntb = (wv >> 1) * 4;
    f32x4 acc2[4];
    #pragma unroll
    for (int t = 0; t < 4; t++) acc2[t] = (f32x4){0.f, 0.f, 0.f, 0.f};
    #pragma unroll
    for (int s = 0; s < 4; s++) {
        bf16x8 a = *(const bf16x8*)&As[(mt * 16 + m) * 136 + quad * 8 + s * 32];
        #pragma unroll
        for (int t = 0; t < 4; t++) {
            int n = (ntb + t) * 16 + m;
            bf16x8 b = *(const bf16x8*)&Wt[n * D + quad * 8 + s * 32];
            acc2[t] = __builtin_amdgcn_mfma_f32_16x16x32_bf16(a, b, acc2[t], 0, 0, 0);
        }
    }
    int orow0 = p * PNODES + mt * 16 + quad * 4;
    #pragma unroll
    for (int t = 0; t < 4; t++) {
        int n = (ntb + t) * 16 + m;
        float bz = bias[n];
        #pragma unroll
        for (int r = 0; r < 4; r++) {
            int grow = orow0 + r;
            if (grow < N) out[(size_t)grow * D + n] = acc2[t][r] + bz;
        }
    }
}

extern "C" void kernel_launch(void* const* d_in, const int* in_sizes, int n_in,
                              void* d_out, int out_size, void* d_ws, size_t ws_size,
                              hipStream_t stream) {
    const float* h    = (const float*)d_in[0];
    const int*   src  = (const int*)d_in[1];
    const int*   dst  = (const int*)d_in[2];
    const int*   dist = (const int*)d_in[3];
    const float* W    = (const float*)d_in[4];
    const float* bias = (const float*)d_in[5];
    float* out = (float*)d_out;
    const int N = in_sizes[0] / D;
    const int E = in_sizes[1];

    const int NW = (N + 1) / 2;                        // packed histogram words
    const int hchunk = (((E + HC - 1) / HC) + 3) & ~3; // per-copy edges, %4==0
    const int P = (N + PNODES - 1) / PNODES;           // 1563 dst partitions
    const int nbA = (E + CHUNK - 1) / CHUNK;           // 98 partition blocks

    char* ws = (char*)d_ws;
    size_t p = 0;
    auto alloc = [&](size_t bytes) -> char* {
        char* r = ws + p;
        p = (p + bytes + 511) & ~(size_t)511;
        return r;
    };
    int* gcur = (int*)alloc((size_t)P * 4);
    unsigned int* gdeg = (unsigned int*)alloc((size_t)NW * 4);         // 100 KB
    unsigned int* gbuf = (unsigned int*)alloc((size_t)P * PCAP * 4);   // 4.8 MB
    unsigned short* hs = (unsigned short*)alloc((size_t)N * D * 2);    // 12.8 MB
    unsigned short* Wt = (unsigned short*)alloc((size_t)D * D * 2);

    // dynamic LDS: partition role needs 2*CHUNK + 4*P ints; hist role NW words
    size_t dyn_part = ((size_t)2 * CHUNK + 4 * P) * 4;
    size_t dyn_hist = (size_t)NW * 4;
    size_t dyn_sz = dyn_part > dyn_hist ? dyn_part : dyn_hist;

    // one memset covers gcur + gdeg (adjacent in workspace)
    hipMemsetAsync(gcur, 0, (size_t)((char*)gdeg - (char*)gcur) + (size_t)NW * 4,
                   stream);
    k_combo<<<nbA + HC + 1 + NCAST, 256, dyn_sz, stream>>>(src, dst, dist,
            gcur, gbuf, gdeg, (const float4*)h, (uint4*)hs, W, Wt,
            E, N, NW, hchunk, P, nbA);
    k_pagg<<<P, 256, 0, stream>>>((const uint4*)hs, gbuf, gcur,
            (const unsigned short*)gdeg, Wt, bias, out, N);
}

// Round 7
// 153.242 us; speedup vs baseline: 1.1994x; 1.1994x over previous
//
#include <hip/hip_runtime.h>

// DGCN layer: out = ((A_norm @ (h * outdeg^-.5)) * indeg^-1.5) @ W + bias
// R16: revert R15 (LDS-staged pipeline halved occupancy: TLP, not in-wave
// pipelining, hides this gather). Base = R14 (best, ~43us pagg). Changes:
// (1) k_pagg __launch_bounds__(256,8): 18.3KB LDS x8 = 147KB, VGPR 36 < 64
//     -> 8 blocks/CU (was 6), +33% in-flight gathers.
// (2) k_combo 2 blocks/CU: CHUNK 6144 (partition LDS 72.4KB) + histogram
//     split into 2 half-range sweeps (64 blocks, 48.8KB bins, each edge
//     chunk read by both halves) -> dyn 72.4KB, 580 blocks ~1.1 rounds.
// Pipeline: memset(gcur+gdeg) + combo(partition|hist|Wcast|hcast) + pagg.

constexpr int D = 128;
constexpr int HC = 32;        // histogram edge-chunks (x2 halves = 64 blocks)
constexpr int PNODES = 32;    // dst-nodes per partition
constexpr int PCAP = 768;     // edge capacity per partition (mean 512, +11 sigma)
constexpr int CHUNK = 6144;   // edges per partition-sort block
constexpr int NCAST = 384;    // h-cast backfill blocks

typedef __attribute__((ext_vector_type(8))) short bf16x8;
typedef __attribute__((ext_vector_type(4))) float f32x4;
typedef __attribute__((ext_vector_type(2))) _Float16 f16x2;

__device__ __forceinline__ float bf16_to_f(unsigned int u16) {
    union { unsigned int u; float f; } c; c.u = u16 << 16; return c.f;
}
__device__ __forceinline__ unsigned int f_to_bf16(float f) {
    union { float f; unsigned int u; } c; c.f = f;
    unsigned int u = c.u;
    u += 0x7fffu + ((u >> 16) & 1u);   // RNE
    return u >> 16;
}
__device__ __forceinline__ unsigned int pack_f16x2(float x, float y) {
    f16x2 p; p.x = (_Float16)x; p.y = (_Float16)y;   // RNE cvt
    union { f16x2 h; unsigned int u; } c; c.h = p; return c.u;
}

// ---- combined kernel, role by blockIdx:
//   [0, nbA)             partition edges by dst (chunked LDS counting sort)
//   [nbA, nbA+2*HC)      out-degree histogram, half node-range per block
//   nbA+2*HC             W fp32 -> Wt bf16 transposed
//   (nbA+2*HC, ...]      h fp32 -> hs fp16 (unscaled) ----
__global__ __launch_bounds__(256) void k_combo(const int* __restrict__ src,
        const int* __restrict__ dst, const int* __restrict__ dist,
        int* __restrict__ gcur, unsigned int* __restrict__ gbuf,
        unsigned int* __restrict__ gdeg,
        const float4* __restrict__ h4, uint4* __restrict__ hs4,
        const float* __restrict__ W, unsigned short* __restrict__ Wt,
        int E, int N, int NW, int NWH, int hchunk, int P, int nbA) {
    extern __shared__ int dyn[];
    int tid = threadIdx.x;
    int bi = blockIdx.x;

    if (bi >= nbA + 2 * HC) {
        if (bi == nbA + 2 * HC) {    // W[k][n] fp32 -> Wt[n*128+k] bf16
            for (int i = tid; i < D * D; i += 256) {
                int k = i >> 7, n = i & 127;
                Wt[n * D + k] = (unsigned short)f_to_bf16(W[i]);
            }
            return;
        }
        // ---- hcast role: hs = fp16(h), grid-stride over 8-float groups ----
        int cb = bi - (nbA + 2 * HC + 1);
        int G = N * (D / 8);
        for (int i = cb * 256 + tid; i < G; i += NCAST * 256) {
            float4 a = h4[2 * i];
            float4 b = h4[2 * i + 1];
            uint4 o;
            o.x = pack_f16x2(a.x, a.y);
            o.y = pack_f16x2(a.z, a.w);
            o.z = pack_f16x2(b.x, b.y);
            o.w = pack_f16x2(b.z, b.w);
            hs4[i] = o;
        }
        return;
    }

    if (bi >= nbA) {
        // ---- hist role: half-range packed u16 histogram in LDS (48.8 KB).
        //      Block covers node words [half*NWH, min((half+1)*NWH, NW));
        //      each edge chunk is scanned by both halves. ----
        unsigned int* bins = (unsigned int*)dyn;
        int c = bi - nbA;            // 0 .. 2*HC-1
        int half = c >> 5;           // c / HC
        int cc = c & 31;             // c % HC
        int wlo = half * NWH;
        int whi = min(wlo + NWH, NW);
        int nwh = whi - wlo;
        for (int i = tid; i < nwh; i += 256) bins[i] = 0;
        __syncthreads();
        int e0 = cc * hchunk, e1 = min(e0 + hchunk, E);
        for (int i = e0 + tid * 4; i < e1; i += 1024) {
            if (i + 3 < e1) {
                int4 k4 = *(const int4*)&src[i];
                #pragma unroll
                for (int j = 0; j < 4; j++) {
                    int sv = (&k4.x)[j];
                    int wi = sv >> 1;
                    if (wi >= wlo && wi < whi)
                        atomicAdd(&bins[wi - wlo], 1u << ((sv & 1) * 16));
                }
            } else {
                for (int e = i; e < e1; e++) {
                    int wi = src[e] >> 1;
                    if (wi >= wlo && wi < whi)
                        atomicAdd(&bins[wi - wlo], 1u << ((src[e] & 1) * 16));
                }
            }
        }
        __syncthreads();
        // reduce in place: packed u32 add is exact (halves never carry)
        for (int i = tid; i < nwh; i += 256) {
            unsigned int v = bins[i];
            if (v) atomicAdd(&gdeg[wlo + i], v);
        }
        return;
    }

    // ---- partition role: chunked counting sort into 32-node dst buckets ----
    // Packed edge word: src (16b) | dst_lo (5b @16) | dist (3b @21).
    unsigned int* sorted = (unsigned int*)dyn;            // CHUNK
    int* gidx  = dyn + CHUNK;                             // CHUNK
    int* hist  = dyn + 2 * CHUNK;                         // P
    int* start = hist + P;
    int* lofs  = start + P;
    int* base_g = lofs + P;
    __shared__ int wsum[4];

    int lane = tid & 63, w = tid >> 6;
    int e0 = bi * CHUNK;
    int e1 = min(e0 + CHUNK, E);
    int ce = e1 - e0;

    for (int b = tid; b < P; b += 256) hist[b] = 0;
    __syncthreads();

    // phase 1: histogram dst partitions
    for (int i = e0 + tid * 4; i < e1; i += 1024) {
        if (i + 3 < e1) {
            int4 d4 = *(const int4*)&dst[i];
            atomicAdd(&hist[d4.x >> 5], 1);
            atomicAdd(&hist[d4.y >> 5], 1);
            atomicAdd(&hist[d4.z >> 5], 1);
            atomicAdd(&hist[d4.w >> 5], 1);
        } else {
            for (int e = i; e < e1; e++) atomicAdd(&hist[dst[e] >> 5], 1);
        }
    }
    __syncthreads();

    // phase 2: scan (7 bins/thread) + global reservation
    int loc[7];
    int s = 0;
    #pragma unroll
    for (int j = 0; j < 7; j++) {
        int b = tid * 7 + j;
        int v = (b < P) ? hist[b] : 0;
        loc[j] = s;
        s += v;
    }
    int x = s;
    #pragma unroll
    for (int off = 1; off < 64; off <<= 1) {
        int t = __shfl_up(x, off, 64);
        if (lane >= off) x += t;
    }
    if (lane == 63) wsum[w] = x;
    __syncthreads();
    int tbase = x - s;
    #pragma unroll
    for (int k = 0; k < 4; k++) if (k < w) tbase += wsum[k];
    #pragma unroll
    for (int j = 0; j < 7; j++) {
        int b = tid * 7 + j;
        if (b < P) {
            int st = tbase + loc[j];
            start[b] = st;
            lofs[b] = st;
            int cnt = hist[b];
            if (cnt) base_g[b] = atomicAdd(&gcur[b], cnt);
        }
    }
    __syncthreads();

    // phase 3: re-read edges (L2-hot), place into LDS order + targets
    for (int i = e0 + tid * 4; i < e1; i += 1024) {
        if (i + 3 < e1) {
            int4 s4 = *(const int4*)&src[i];
            int4 d4 = *(const int4*)&dst[i];
            int4 q4 = *(const int4*)&dist[i];
            #pragma unroll
            for (int j = 0; j < 4; j++) {
                int sv = (&s4.x)[j], dv = (&d4.x)[j], qv = (&q4.x)[j];
                int p = dv >> 5;
                unsigned int wd = (unsigned)sv | ((unsigned)(dv & 31) << 16)
                                | ((unsigned)qv << 21);
                int pos = atomicAdd(&lofs[p], 1);
                sorted[pos] = wd;
                int rank = base_g[p] + (pos - start[p]);
                gidx[pos] = (rank < PCAP) ? p * PCAP + rank : -1;
            }
        } else {
            for (int e = i; e < e1; e++) {
                int sv = src[e], dv = dst[e], qv = dist[e];
                int p = dv >> 5;
                unsigned int wd = (unsigned)sv | ((unsigned)(dv & 31) << 16)
                                | ((unsigned)qv << 21);
                int pos = atomicAdd(&lofs[p], 1);
                sorted[pos] = wd;
                int rank = base_g[p] + (pos - start[p]);
                gidx[pos] = (rank < PCAP) ? p * PCAP + rank : -1;
            }
        }
    }
    __syncthreads();

    // phase 4: run-coalesced copy-out
    for (int i = tid; i < ce; i += 256) {
        int g = gidx[i];
        if (g >= 0) gbuf[g] = sorted[i];
    }
}

// ---- per-partition aggregate + fused MFMA GEMM epilogue ----
// Edges LDS-sorted by node; waves process nodes wave-uniformly. Per-edge
// coeff (2^-dist * outdeg^-0.5) precomputed into LDS scoef[] at slist build
// -> steady-state inner loop is LDS-only except the row-gather payload.
// Per node: up to 8 row-gathers (32 edges) issued before compute with
// wave-uniform guards. fp16 rows -> cvt+fma (v_fma_mix, f32 acc);
// shfl_xor(16,32) fold. 32x128 agg -> LDS -> MFMA. 8 blocks/CU (18.3KB LDS).
__global__ __launch_bounds__(256, 8) void k_pagg(const uint4* __restrict__ hs4,
        const unsigned int* __restrict__ gbuf, const int* __restrict__ gcur,
        const unsigned short* __restrict__ gdeg16,
        const unsigned short* __restrict__ Wt, const float* __restrict__ bias,
        float* __restrict__ out, int N) {
    __shared__ unsigned int elist[PCAP];
    __shared__ unsigned int slist[PCAP];
    __shared__ float scoef[PCAP];
    __shared__ int h2[PNODES], st2[PNODES], lo2[PNODES];
    __shared__ unsigned short As[PNODES * 136];
    int p = blockIdx.x;
    int tid = threadIdx.x;
    int cnt = min(gcur[p], PCAP);
    const unsigned int* gp = gbuf + (size_t)p * PCAP;

    if (tid < PNODES) h2[tid] = 0;
    __syncthreads();
    for (int i = tid; i < cnt; i += 256) {
        unsigned int wd = gp[i];
        elist[i] = wd;
        atomicAdd(&h2[(wd >> 16) & 31], 1);
    }
    __syncthreads();
    if (tid < 64) {   // wave 0 scans 32 bins
        int v = (tid < PNODES) ? h2[tid] : 0;
        int x = v;
        #pragma unroll
        for (int off = 1; off < 32; off <<= 1) {
            int t = __shfl_up(x, off, 64);
            if ((tid & 63) >= off) x += t;
        }
        if (tid < PNODES) { st2[tid] = x - v; lo2[tid] = x - v; }
    }
    __syncthreads();
    for (int i = tid; i < cnt; i += 256) {
        unsigned int wd = elist[i];
        int pos = atomicAdd(&lo2[(wd >> 16) & 31], 1);
        slist[pos] = wd;
        unsigned int sv = wd & 0xffffu;
        float os = rsqrtf((float)gdeg16[sv]);             // outdeg^-0.5 (once)
        scoef[pos] = __uint_as_float((127u - ((wd >> 21) & 7u)) << 23) * os;
    }
    __syncthreads();

    int wv = tid >> 6, l64 = tid & 63;
    int lane16 = l64 & 15, sub = l64 >> 4;   // edge slot 0..3
    #pragma unroll
    for (int k = 0; k < 8; k++) {
        int dl = wv * 8 + k;
        int node = p * PNODES + dl;
        int deg = h2[dl], b = st2[dl];
        float acc[8] = {0.f, 0.f, 0.f, 0.f, 0.f, 0.f, 0.f, 0.f};
        for (int eo = 0; eo < deg; eo += 32) {
            uint4 hv[8];
            float cc[8];
            // issue all of this node's gathers before any compute
            #pragma unroll
            for (int j = 0; j < 8; j++) {
                if (eo + j * 4 < deg) {          // wave-uniform guard
                    int off = eo + j * 4 + sub;
                    bool valid = off < deg;
                    int ei = b + (valid ? off : 0);
                    unsigned int wd = slist[ei];
                    float c0 = scoef[ei];                 // LDS broadcast
                    cc[j] = valid ? c0 : 0.f;
                    hv[j] = hs4[((wd & 0xffffu) << 4) + (unsigned)lane16];
                }
            }
            #pragma unroll
            for (int j = 0; j < 8; j++) {
                if (eo + j * 4 < deg) {          // wave-uniform guard
                    float c = cc[j];
                    const f16x2* hp = (const f16x2*)&hv[j];
                    #pragma unroll
                    for (int q = 0; q < 4; q++) {
                        acc[2 * q]     = fmaf((float)hp[q].x, c, acc[2 * q]);
                        acc[2 * q + 1] = fmaf((float)hp[q].y, c, acc[2 * q + 1]);
                    }
                }
            }
        }
        #pragma unroll
        for (int j = 0; j < 8; j++) {   // fold 4 edge slots
            acc[j] += __shfl_xor(acc[j], 16, 64);
            acc[j] += __shfl_xor(acc[j], 32, 64);
        }
        if (sub == 0) {
            uint4 o = make_uint4(0u, 0u, 0u, 0u);
            if (node < N) {
                float fd = (float)deg;
                float sc = rsqrtf(fd) / fd;   // indeg^-1.5
                o.x = f_to_bf16(acc[0] * sc) | (f_to_bf16(acc[1] * sc) << 16);
                o.y = f_to_bf16(acc[2] * sc) | (f_to_bf16(acc[3] * sc) << 16);
                o.z = f_to_bf16(acc[4] * sc) | (f_to_bf16(acc[5] * sc) << 16);
                o.w = f_to_bf16(acc[6] * sc) | (f_to_bf16(acc[7] * sc) << 16);
            }
            *(uint4*)&As[dl * 136 + lane16 * 8] = o;
        }
    }
    __syncthreads();

    // MFMA: wave w -> row-tile mt = w&1, col-tiles nt = (w>>1)*4 + t
    int m = l64 & 15, quad = l64 >> 4;
    int mt = wv & 1, ntb = (wv >> 1) * 4;
    f32x4 acc2[4];
    #pragma unroll
    for (int t = 0; t < 4; t++) acc2[t] = (f32x4){0.f, 0.f, 0.f, 0.f};
    #pragma unroll
    for (int s = 0; s < 4; s++) {
        bf16x8 a = *(const bf16x8*)&As[(mt * 16 + m) * 136 + quad * 8 + s * 32];
        #pragma unroll
        for (int t = 0; t < 4; t++) {
            int n = (ntb + t) * 16 + m;
            bf16x8 b = *(const bf16x8*)&Wt[n * D + quad * 8 + s * 32];
            acc2[t] = __builtin_amdgcn_mfma_f32_16x16x32_bf16(a, b, acc2[t], 0, 0, 0);
        }
    }
    int orow0 = p * PNODES + mt * 16 + quad * 4;
    #pragma unroll
    for (int t = 0; t < 4; t++) {
        int n = (ntb + t) * 16 + m;
        float bz = bias[n];
        #pragma unroll
        for (int r = 0; r < 4; r++) {
            int grow = orow0 + r;
            if (grow < N) out[(size_t)grow * D + n] = acc2[t][r] + bz;
        }
    }
}

extern "C" void kernel_launch(void* const* d_in, const int* in_sizes, int n_in,
                              void* d_out, int out_size, void* d_ws, size_t ws_size,
                              hipStream_t stream) {
    const float* h    = (const float*)d_in[0];
    const int*   src  = (const int*)d_in[1];
    const int*   dst  = (const int*)d_in[2];
    const int*   dist = (const int*)d_in[3];
    const float* W    = (const float*)d_in[4];
    const float* bias = (const float*)d_in[5];
    float* out = (float*)d_out;
    const int N = in_sizes[0] / D;
    const int E = in_sizes[1];

    const int NW = (N + 1) / 2;                        // packed histogram words
    const int NWH = (NW + 1) / 2;                      // words per hist half
    const int hchunk = (((E + HC - 1) / HC) + 3) & ~3; // per-copy edges, %4==0
    const int P = (N + PNODES - 1) / PNODES;           // 1563 dst partitions
    const int nbA = (E + CHUNK - 1) / CHUNK;           // 131 partition blocks

    char* ws = (char*)d_ws;
    size_t p = 0;
    auto alloc = [&](size_t bytes) -> char* {
        char* r = ws + p;
        p = (p + bytes + 511) & ~(size_t)511;
        return r;
    };
    int* gcur = (int*)alloc((size_t)P * 4);
    unsigned int* gdeg = (unsigned int*)alloc((size_t)NW * 4);         // 100 KB
    unsigned int* gbuf = (unsigned int*)alloc((size_t)P * PCAP * 4);   // 4.8 MB
    unsigned short* hs = (unsigned short*)alloc((size_t)N * D * 2);    // 12.8 MB
    unsigned short* Wt = (unsigned short*)alloc((size_t)D * D * 2);

    // dynamic LDS: partition 2*CHUNK+4*P ints (72.4 KB); hist NWH words (48.8)
    size_t dyn_part = ((size_t)2 * CHUNK + 4 * P) * 4;
    size_t dyn_hist = (size_t)NWH * 4;
    size_t dyn_sz = dyn_part > dyn_hist ? dyn_part : dyn_hist;

    // one memset covers gcur + gdeg (adjacent in workspace)
    hipMemsetAsync(gcur, 0, (size_t)((char*)gdeg - (char*)gcur) + (size_t)NW * 4,
                   stream);
    k_combo<<<nbA + 2 * HC + 1 + NCAST, 256, dyn_sz, stream>>>(src, dst, dist,
            gcur, gbuf, gdeg, (const float4*)h, (uint4*)hs, W, Wt,
            E, N, NW, NWH, hchunk, P, nbA);
    k_pagg<<<P, 256, 0, stream>>>((const uint4*)hs, gbuf, gcur,
            (const unsigned short*)gdeg, Wt, bias, out, N);
}